// Round 1
// baseline (111.325 us; speedup 1.0000x reference)
//
#include <hip/hip_runtime.h>

#define BSZ 256
#define DDIM 1024
#define MARGIN 0.2f

// Kernel 1: scores[i*B+j] = dot(im[j], s[i*B+j])
// One wave (64 lanes) per (i,j) pair; 4 waves per block.
__global__ __launch_bounds__(256) void scores_kernel(const float* __restrict__ im,
                                                     const float* __restrict__ s,
                                                     float* __restrict__ scores) {
    const int wave = threadIdx.x >> 6;
    const int lane = threadIdx.x & 63;
    const int p = blockIdx.x * 4 + wave;        // pair index in [0, B*B)
    const int j = p & (BSZ - 1);

    const float4* sp = reinterpret_cast<const float4*>(s + (size_t)p * DDIM);
    const float4* ip = reinterpret_cast<const float4*>(im + (size_t)j * DDIM);

    float acc = 0.0f;
#pragma unroll
    for (int k = 0; k < 4; ++k) {
        float4 a = sp[k * 64 + lane];
        float4 b = ip[k * 64 + lane];
        acc += a.x * b.x + a.y * b.y + a.z * b.z + a.w * b.w;
    }
#pragma unroll
    for (int off = 32; off > 0; off >>= 1) acc += __shfl_down(acc, off);
    if (lane == 0) scores[p] = acc;
}

// Kernel 2: contrastive-margin epilogue over the BxB score matrix.
// Thread t owns row t (cost_s) and column t (cost_im); both use diag[t].
__global__ __launch_bounds__(256) void loss_kernel(const float* __restrict__ scores,
                                                   float* __restrict__ out) {
    const int t = threadIdx.x;
    __shared__ float diag_s[BSZ];
    __shared__ float wsum[4];

    diag_s[t] = scores[t * BSZ + t];
    __syncthreads();
    const float dg = diag_s[t];

    float rowmax = 0.0f;  // includes the 0 entry at j==t (masked diagonal)
    float colmax = 0.0f;
    for (int j = 0; j < BSZ; ++j) {
        if (j != t) {
            rowmax = fmaxf(rowmax, MARGIN + scores[t * BSZ + j] - dg);
            colmax = fmaxf(colmax, MARGIN + scores[j * BSZ + t] - dg);
        }
    }
    float v = fmaxf(rowmax, 0.0f) + fmaxf(colmax, 0.0f);

    // block reduce-sum: wave shuffle then LDS across the 4 waves
#pragma unroll
    for (int off = 32; off > 0; off >>= 1) v += __shfl_down(v, off);
    const int wave = t >> 6;
    const int lane = t & 63;
    if (lane == 0) wsum[wave] = v;
    __syncthreads();
    if (t == 0) out[0] = wsum[0] + wsum[1] + wsum[2] + wsum[3];
}

extern "C" void kernel_launch(void* const* d_in, const int* in_sizes, int n_in,
                              void* d_out, int out_size, void* d_ws, size_t ws_size,
                              hipStream_t stream) {
    const float* im = (const float*)d_in[0];   // [B, D]
    const float* s  = (const float*)d_in[1];   // [B, B, D]
    float* out = (float*)d_out;                // scalar
    float* scores = (float*)d_ws;              // B*B floats = 256 KB scratch

    const int nPairs = BSZ * BSZ;              // 65536
    scores_kernel<<<nPairs / 4, 256, 0, stream>>>(im, s, scores);
    loss_kernel<<<1, 256, 0, stream>>>(scores, out);
}

// Round 2
// 46.943 us; speedup vs baseline: 2.3715x; 2.3715x over previous
//
#include <hip/hip_runtime.h>

#define BSZ 256
#define DDIM 1024
#define MARGIN 0.2f
#define WPB 4   // waves per block
#define PPW 8   // pairs (i values) per wave

// Kernel 1: scores[i*B+j] = dot(im[j], s[i,j,:])
// One wave per (j, i-octet): im[j] loaded into registers once, then 8 rows
// of s are streamed against it. 8192 waves = 32/CU.
__global__ __launch_bounds__(256) void scores_kernel(const float* __restrict__ im,
                                                     const float* __restrict__ s,
                                                     float* __restrict__ scores) {
    const int wave = threadIdx.x >> 6;
    const int lane = threadIdx.x & 63;
    const int w = blockIdx.x * WPB + wave;        // wave id in [0, 8192)
    const int j = w & (BSZ - 1);
    const int iBase = (w >> 8) * PPW;

    const float4* ip = reinterpret_cast<const float4*>(im + (size_t)j * DDIM);
    float4 b0 = ip[0 * 64 + lane];
    float4 b1 = ip[1 * 64 + lane];
    float4 b2 = ip[2 * 64 + lane];
    float4 b3 = ip[3 * 64 + lane];

#pragma unroll
    for (int it = 0; it < PPW; ++it) {
        const int p = (iBase + it) * BSZ + j;
        const float4* sp = reinterpret_cast<const float4*>(s + (size_t)p * DDIM);
        float4 a0 = sp[0 * 64 + lane];
        float4 a1 = sp[1 * 64 + lane];
        float4 a2 = sp[2 * 64 + lane];
        float4 a3 = sp[3 * 64 + lane];
        float acc = a0.x * b0.x + a0.y * b0.y + a0.z * b0.z + a0.w * b0.w;
        acc += a1.x * b1.x + a1.y * b1.y + a1.z * b1.z + a1.w * b1.w;
        acc += a2.x * b2.x + a2.y * b2.y + a2.z * b2.z + a2.w * b2.w;
        acc += a3.x * b3.x + a3.y * b3.y + a3.z * b3.z + a3.w * b3.w;
#pragma unroll
        for (int off = 32; off > 0; off >>= 1) acc += __shfl_down(acc, off);
        if (lane == 0) scores[p] = acc;
    }
}

// Kernel 2: block t computes rowmax(relu(margin + S[t,:] - dg)) and
// colmax(relu(margin + S[:,t] - dg)), dg = S[t,t]; writes partial[t].
__global__ __launch_bounds__(256) void rowcol_kernel(const float* __restrict__ scores,
                                                     float* __restrict__ partial) {
    const int t = blockIdx.x;
    const int j = threadIdx.x;
    __shared__ float wr[4], wc[4];

    const float dg = scores[t * BSZ + t];
    float rowv = 0.0f, colv = 0.0f;
    if (j != t) {
        rowv = fmaxf(MARGIN + scores[t * BSZ + j] - dg, 0.0f);
        colv = fmaxf(MARGIN + scores[j * BSZ + t] - dg, 0.0f);
    }
#pragma unroll
    for (int off = 32; off > 0; off >>= 1) {
        rowv = fmaxf(rowv, __shfl_down(rowv, off));
        colv = fmaxf(colv, __shfl_down(colv, off));
    }
    const int wave = j >> 6;
    const int lane = j & 63;
    if (lane == 0) { wr[wave] = rowv; wc[wave] = colv; }
    __syncthreads();
    if (j == 0) {
        float rm = fmaxf(fmaxf(wr[0], wr[1]), fmaxf(wr[2], wr[3]));
        float cm = fmaxf(fmaxf(wc[0], wc[1]), fmaxf(wc[2], wc[3]));
        partial[t] = rm + cm;
    }
}

// Kernel 3: sum 256 partials -> scalar out (deterministic).
__global__ __launch_bounds__(256) void sum_kernel(const float* __restrict__ partial,
                                                  float* __restrict__ out) {
    const int t = threadIdx.x;
    __shared__ float wsum[4];
    float v = partial[t];
#pragma unroll
    for (int off = 32; off > 0; off >>= 1) v += __shfl_down(v, off);
    if ((t & 63) == 0) wsum[t >> 6] = v;
    __syncthreads();
    if (t == 0) out[0] = wsum[0] + wsum[1] + wsum[2] + wsum[3];
}

extern "C" void kernel_launch(void* const* d_in, const int* in_sizes, int n_in,
                              void* d_out, int out_size, void* d_ws, size_t ws_size,
                              hipStream_t stream) {
    const float* im = (const float*)d_in[0];   // [B, D]
    const float* s  = (const float*)d_in[1];   // [B, B, D]
    float* out = (float*)d_out;                // scalar
    float* scores  = (float*)d_ws;             // B*B floats
    float* partial = scores + BSZ * BSZ;       // B floats

    const int nWaves = (BSZ * BSZ) / PPW;      // 8192
    scores_kernel<<<nWaves / WPB, 256, 0, stream>>>(im, s, scores);
    rowcol_kernel<<<BSZ, 256, 0, stream>>>(scores, partial);
    sum_kernel<<<1, 256, 0, stream>>>(partial, out);
}